// Round 1
// baseline (20457.582 us; speedup 1.0000x reference)
//
#include <hip/hip_runtime.h>
#include <hip/hip_bf16.h>
#include <stdint.h>

// Problem sizes (fixed)
#define Bc 32
#define Tc 4096
#define Dc 256
#define Uc 256
#define Kc 512
#define NWG 16     // workgroups; each owns 16 units (=64 gate columns)
#define THR 128    // 2 waves per WG
#define RINGM 3    // ring of 4 state slots

typedef __bf16 bf16x8 __attribute__((ext_vector_type(8)));
typedef float f32x16 __attribute__((ext_vector_type(16)));

__device__ __forceinline__ float sigm(float x){ return 1.0f/(1.0f+__expf(-x)); }
__device__ __forceinline__ float tanh_(float x){ return 1.0f-2.0f/(__expf(2.0f*x)+1.0f); }
__device__ __forceinline__ unsigned short bf16rn(float f){
  unsigned int u = __builtin_bit_cast(unsigned int, f);
  u = (u + 0x7fffu + ((u>>16)&1u)) >> 16;
  return (unsigned short)u;
}

// x [B][T][D] f32  ->  xT [T][B][D] bf16 (time-major, contiguous 16KB per step)
__global__ void xt_kernel(const float* __restrict__ x, unsigned short* __restrict__ xT){
  int i4 = blockIdx.x*blockDim.x + threadIdx.x;
  if (i4 >= (Bc*Tc*Dc)/4) return;
  const float4 v = *(const float4*)(x + (size_t)i4*4);
  int d4 = i4 & 63;
  int t  = (i4 >> 6) & 4095;
  int b  = i4 >> 18;
  uint2 pk;
  pk.x = (unsigned)bf16rn(v.x) | ((unsigned)bf16rn(v.y)<<16);
  pk.y = (unsigned)bf16rn(v.z) | ((unsigned)bf16rn(v.w)<<16);
  *(uint2*)(xT + ((size_t)(t*Bc + b)*Dc + d4*4)) = pk;
}

// Persistent recurrent kernel.
// Each WG g owns units [g*16, g*16+16). Wave w (0/1) of the WG owns 8 units,
// i.e. 32 gate-columns {gate*8+du}, with their [512 x 32] bf16 weight slice
// resident in 128 VGPRs (32 K-tiles of bf16x8 B-fragments).
// Per step: stage x(t) (prefetched) + s(t) (global exchange) into swizzled LDS,
// 32x MFMA 32x32x16, z->LDS, gates/state elementwise, publish ct, release flag.
template<int USE_XT>
__global__ __launch_bounds__(THR, 1) void lstm_kernel(
    const float* __restrict__ x,
    const float* __restrict__ h0,
    const float* __restrict__ Wf, const float* __restrict__ Wi,
    const float* __restrict__ Wc, const float* __restrict__ Wo,
    float* __restrict__ out,
    const unsigned short* __restrict__ xT,
    unsigned short* __restrict__ Sring,   // [4][32][256] bf16
    int* __restrict__ flags)              // [4][NWG][16] (64B stride per flag)
{
  __shared__ __align__(16) char act_s[32*512];  // s-part A, bf16, XOR-swizzled
  __shared__ __align__(16) char act_x[32*512];  // x-part A
  __shared__ float zbuf[32][68];                // z slice [32 rows][4 gates x 16 units]

  const int tid  = threadIdx.x;
  const int wg   = blockIdx.x;
  const int wave = tid >> 6;
  const int lane = tid & 63;

  // ---------- one-time: load resident B fragments ----------
  const int colw  = lane & 31;
  const int khalf = lane >> 5;
  const int gate  = colw >> 3;
  const int du    = colw & 7;
  const int unit  = wg*16 + wave*8 + du;
  const float* Wm = (gate==0)?Wf:(gate==1)?Wi:(gate==2)?Wc:Wo;
  bf16x8 Bres[32];
  #pragma unroll
  for (int kt=0; kt<32; ++kt){
    union { bf16x8 v; unsigned short s[8]; } bb;
    #pragma unroll
    for (int i=0;i<8;++i){
      int k = kt*16 + khalf*8 + i;
      bb.s[i] = bf16rn(Wm[k*Uc + unit]);
    }
    Bres[kt] = bb.v;
  }

  // ---------- per-thread recurrent cell state (4 units of one chain) ----------
  const int brow = tid >> 2;   // chain 0..31
  const int q    = tid & 3;    // unit quad within WG's 16 units
  float sst[4];
  #pragma unroll
  for (int j=0;j<4;++j) sst[j] = h0[brow*Uc + wg*16 + q*4 + j];

  // staging helpers: each thread moves one 16B granule x 8
  const int srow = tid >> 5;          // + j*4
  const int sbo  = (tid & 31) * 16;

  // prime x prefetch for t=0
  uint4 xp[8];
  if (USE_XT){
    #pragma unroll
    for (int j=0;j<8;++j)
      xp[j] = *(const uint4*)((const char*)xT + (size_t)j*2048 + (size_t)tid*16);
  }

  for (int t=0; t<Tc; ++t){
    // ---- stage x(t) into act_x (swizzled) ----
    if (USE_XT){
      #pragma unroll
      for (int j=0;j<8;++j){
        int row = j*4 + srow;
        *(uint4*)(act_x + row*512 + (sbo ^ ((row&15)<<4))) = xp[j];
      }
    } else {
      #pragma unroll
      for (int j=0;j<8;++j){
        int row = j*4 + srow;
        const float* src = x + (size_t)row*Tc*Dc + (size_t)t*Dc + (tid&31)*8;
        float4 lo = *(const float4*)(src);
        float4 hi = *(const float4*)(src+4);
        union { uint4 u; unsigned short s[8]; } pk;
        pk.s[0]=bf16rn(lo.x); pk.s[1]=bf16rn(lo.y); pk.s[2]=bf16rn(lo.z); pk.s[3]=bf16rn(lo.w);
        pk.s[4]=bf16rn(hi.x); pk.s[5]=bf16rn(hi.y); pk.s[6]=bf16rn(hi.z); pk.s[7]=bf16rn(hi.w);
        *(uint4*)(act_x + row*512 + (sbo ^ ((row&15)<<4))) = pk.u;
      }
    }

    // ---- stage s(t) into act_s ----
    if (t == 0){
      #pragma unroll
      for (int j=0;j<8;++j){
        const float* src = h0 + brow*Uc + q*64 + j*8;
        float4 lo = *(const float4*)(src);
        float4 hi = *(const float4*)(src+4);
        union { uint4 u; unsigned short s[8]; } pk;
        pk.s[0]=bf16rn(lo.x); pk.s[1]=bf16rn(lo.y); pk.s[2]=bf16rn(lo.z); pk.s[3]=bf16rn(lo.w);
        pk.s[4]=bf16rn(hi.x); pk.s[5]=bf16rn(hi.y); pk.s[6]=bf16rn(hi.z); pk.s[7]=bf16rn(hi.w);
        int bo = q*128 + j*16;
        *(uint4*)(act_s + brow*512 + (bo ^ ((brow&15)<<4))) = pk.u;
      }
    } else {
      int* fl = flags + (size_t)(t&RINGM)*NWG*16;
      int v;
      do {
        v = 0x7fffffff;
        if (lane < NWG)
          v = __hip_atomic_load(fl + lane*16, __ATOMIC_ACQUIRE, __HIP_MEMORY_SCOPE_AGENT);
      } while (!__all(v >= t));
      const char* Sp = (const char*)Sring + (size_t)(t&RINGM)*16384;
      #pragma unroll
      for (int j=0;j<8;++j){
        uint4 sv = *(const uint4*)(Sp + (size_t)j*2048 + (size_t)tid*16);
        int row = j*4 + srow;
        *(uint4*)(act_s + row*512 + (sbo ^ ((row&15)<<4))) = sv;
      }
    }

    // ---- issue x(t+1) prefetch ----
    if (USE_XT && (t+1 < Tc)){
      #pragma unroll
      for (int j=0;j<8;++j)
        xp[j] = *(const uint4*)((const char*)xT + (size_t)(t+1)*16384 + (size_t)j*2048 + (size_t)tid*16);
    }

    __syncthreads();

    // ---- MFMA: acc = x(t)@Wx + s(t)@Ws for this wave's 32 columns ----
    f32x16 acc;
    #pragma unroll
    for (int r=0;r<16;++r) acc[r] = 0.0f;
    const int arow = lane & 31;
    #pragma unroll
    for (int kt=0; kt<16; ++kt){     // x part (global K 256..511)
      int bo = (kt*32 + khalf*16) ^ ((arow&15)<<4);
      bf16x8 a = *(const bf16x8*)(act_x + arow*512 + bo);
      acc = __builtin_amdgcn_mfma_f32_32x32x16_bf16(a, Bres[16+kt], acc, 0,0,0);
    }
    #pragma unroll
    for (int kt=0; kt<16; ++kt){     // s part (global K 0..255)
      int bo = (kt*32 + khalf*16) ^ ((arow&15)<<4);
      bf16x8 a = *(const bf16x8*)(act_s + arow*512 + bo);
      acc = __builtin_amdgcn_mfma_f32_32x32x16_bf16(a, Bres[kt], acc, 0,0,0);
    }

    // ---- z -> LDS (verified 32x32 C/D layout) ----
    const int zcol = gate*16 + wave*8 + du;
    #pragma unroll
    for (int r=0;r<16;++r){
      int zrow = (r&3) + 8*(r>>2) + 4*khalf;
      zbuf[zrow][zcol] = acc[r];
    }
    __syncthreads();

    // ---- elementwise gates + state update ----
    float hh[4], cc[4];
    unsigned short pb[4];
    #pragma unroll
    for (int j=0;j<4;++j){
      int lu = q*4 + j;
      float zf = zbuf[brow][lu];
      float zi = zbuf[brow][16+lu];
      float zg = zbuf[brow][32+lu];
      float zo = zbuf[brow][48+lu];
      float f  = sigm(zf);
      float ii = sigm(zi);
      float g  = sigm(zg);
      float o  = tanh_(zo);
      float c  = ii*g + f*sst[j];
      float ct = tanh_(c);
      sst[j] = ct;
      cc[j]  = ct;
      hh[j]  = o*ct;
      pb[j]  = bf16rn(ct);
    }

    if (t+1 < Tc){
      // publish ct slice, fence, release flag (flag ASAP; H/C stores after)
      unsigned short* Sd = Sring + (size_t)((t+1)&RINGM)*8192 + brow*256 + wg*16 + q*4;
      uint2 pkk;
      pkk.x = (unsigned)pb[0] | ((unsigned)pb[1]<<16);
      pkk.y = (unsigned)pb[2] | ((unsigned)pb[3]<<16);
      *(uint2*)Sd = pkk;
      __threadfence();
      __syncthreads();
      if (tid == 0)
        __hip_atomic_store(flags + (size_t)((t+1)&RINGM)*NWG*16 + wg*16, t+1,
                           __ATOMIC_RELEASE, __HIP_MEMORY_SCOPE_AGENT);
    }

    // ---- write H and C outputs ----
    {
      float* Hp = out + (size_t)brow*Tc*Uc + (size_t)t*Uc + wg*16 + q*4;
      float* Cp = Hp + (size_t)Bc*Tc*Uc;
      *(float4*)Hp = make_float4(hh[0],hh[1],hh[2],hh[3]);
      *(float4*)Cp = make_float4(cc[0],cc[1],cc[2],cc[3]);
    }
  }
}

extern "C" void kernel_launch(void* const* d_in, const int* in_sizes, int n_in,
                              void* d_out, int out_size, void* d_ws, size_t ws_size,
                              hipStream_t stream) {
  const float* x  = (const float*)d_in[0];
  const float* h0 = (const float*)d_in[1];
  const float* Wf = (const float*)d_in[2];
  const float* Wi = (const float*)d_in[3];
  const float* Wc = (const float*)d_in[4];
  const float* Wo = (const float*)d_in[5];
  float* out = (float*)d_out;

  char* ws = (char*)d_ws;
  int* flags             = (int*)ws;                          // 4*16*16*4 = 4 KB
  unsigned short* Sring  = (unsigned short*)(ws + 8192);      // 64 KB
  unsigned short* xT     = (unsigned short*)(ws + 8192 + 65536);
  const size_t need = 8192 + 65536 + (size_t)Bc*Tc*Dc*2;      // ~64.07 MB

  hipMemsetAsync(flags, 0xFF, 4096, stream);                  // flags = -1

  if (ws_size >= need){
    int n4 = (Bc*Tc*Dc)/4;
    xt_kernel<<<(n4+255)/256, 256, 0, stream>>>(x, xT);
    lstm_kernel<1><<<NWG, THR, 0, stream>>>(x,h0,Wf,Wi,Wc,Wo,out,xT,Sring,flags);
  } else {
    lstm_kernel<0><<<NWG, THR, 0, stream>>>(x,h0,Wf,Wi,Wc,Wo,out,xT,Sring,flags);
  }
}